// Round 4
// baseline (38589.355 us; speedup 1.0000x reference)
//
#include <hip/hip_runtime.h>

#define T_STEPS 8192
#define NRES    2048
#define DIN     64
#define DOUT    64

typedef unsigned long long u64;
typedef unsigned int u32;

// ---------------------------------------------------------------------------
// ws layout:
//   [0, 64MB)          : states fp32 [T][NRES]
//   [64MB, +48KB)      : ring    u64 [3][NRES]  tagged words {val<<32 | tag}
//   [64MB+48KB, +512KB): WT      fp32 [NRES][DOUT] (W_out transposed)
// ---------------------------------------------------------------------------

__global__ __launch_bounds__(512) void esn_init_ring(u64* __restrict__ ring) {
  int idx = blockIdx.x * 512 + threadIdx.x;
  if (idx < 3 * NRES) ring[idx] = 0ull;
}

__global__ __launch_bounds__(256) void esn_transpose(const float* __restrict__ Wout,
                                                     float* __restrict__ WT) {
  int idx = blockIdx.x * 256 + threadIdx.x;  // 0 .. DOUT*NRES-1
  int d = idx >> 11;                         // / NRES
  int k = idx & (NRES - 1);
  WT[k * DOUT + d] = Wout[idx];
}

// Persistent scan: 256 blocks x 512 threads (8 waves). Wave wv of block b owns
// row r = 8b + wv. Lane l holds W[r][g*256 + 4l + j], g=0..7, j=0..3 (32 regs).
// Protocol (R1, proven): 3-slot ring of tagged u64 {x_bits<<32 | (t+1)},
// relaxed agent-scope atomics (performed at LLC -> cross-XCD safe, no fences).
// Reader at step t polls slot (t-1)%3 for tag==t. Max cross-block skew is 1
// step (a block enters step t+1 only after ALL rows of step t were published),
// so 3 slots can never be overwritten while still being read.
// Single __syncthreads per step: xs is double-buffered, and the barrier bounds
// intra-block skew to 1 step, so staging of step t+1 never touches the buffer
// being read for step t.
__global__ __launch_bounds__(512) void esn_scan(const float* __restrict__ u,
                                                const float* __restrict__ Win,
                                                const float* __restrict__ W,
                                                float* __restrict__ states,
                                                u64* __restrict__ ring) {
  const int tid  = threadIdx.x;
  const int lane = tid & 63;
  const int wv   = tid >> 6;          // 0..7
  const int r    = blockIdx.x * 8 + wv;

  __shared__ float xs[2][NRES];

  // One-time: this wave's W row into registers (coalesced float4).
  float wr[32];
#pragma unroll
  for (int g = 0; g < 8; ++g) {
    const float4 a = *(const float4*)(W + (size_t)r * NRES + g * 256 + lane * 4);
    wr[g * 4 + 0] = a.x; wr[g * 4 + 1] = a.y;
    wr[g * 4 + 2] = a.z; wr[g * 4 + 3] = a.w;
  }
  const float win = Win[r * DIN + lane];

  for (int t = 0; t < T_STEPS; ++t) {
    const float uv = u[t * DIN + lane];  // issue before poll; overlaps the wait
    float* xb = xs[t & 1];
    if (t == 0) {
#pragma unroll
      for (int j = 0; j < 4; ++j) xb[j * 512 + tid] = 0.0f;
    } else {
      const u64* rb  = ring + ((t + 2) % 3) * NRES;  // slot (t-1)%3
      const u32 want = (u32)t;                       // tag written at step t-1
      u64 v[4];
#pragma unroll
      for (int j = 0; j < 4; ++j)
        v[j] = __hip_atomic_load(rb + j * 512 + tid, __ATOMIC_RELAXED,
                                 __HIP_MEMORY_SCOPE_AGENT);
      u32 pend = 0xFu;
      while (pend) {
#pragma unroll
        for (int j = 0; j < 4; ++j) {
          if (pend & (1u << j)) {
            if ((u32)v[j] == want) {   // ready: trickle-stage to LDS now
              xb[j * 512 + tid] = __uint_as_float((u32)(v[j] >> 32));
              pend &= ~(1u << j);
            } else {
              v[j] = __hip_atomic_load(rb + j * 512 + tid, __ATOMIC_RELAXED,
                                       __HIP_MEMORY_SCOPE_AGENT);
            }
          }
        }
      }
    }
    __syncthreads();  // the ONLY barrier per step

    // acc = W_in[r,:] . u_t  +  W[r,:] . x_{t-1}   (32 FMA per lane)
    float acc = win * uv;
#pragma unroll
    for (int g = 0; g < 8; ++g) {
      const float4 xv = *(const float4*)(xb + g * 256 + lane * 4);
      acc = fmaf(wr[g * 4 + 0], xv.x, acc);
      acc = fmaf(wr[g * 4 + 1], xv.y, acc);
      acc = fmaf(wr[g * 4 + 2], xv.z, acc);
      acc = fmaf(wr[g * 4 + 3], xv.w, acc);
    }
    // 64-lane butterfly all-reduce (uniform result on all lanes)
#pragma unroll
    for (int off = 32; off > 0; off >>= 1) acc += __shfl_xor(acc, off, 64);
    const float x = tanhf(acc);  // uniform; computed on all lanes (no shfl tail)
    if (lane == 0) {
      states[(size_t)t * NRES + r] = x;
      const u64 word = ((u64)__float_as_uint(x) << 32) | (u32)(t + 1);
      __hip_atomic_store(ring + (t % 3) * NRES + r, word, __ATOMIC_RELAXED,
                         __HIP_MEMORY_SCOPE_AGENT);
    }
  }
}

// Y = states @ W_out^T + b : block = 16 timesteps; each 64-lane group does 4
// timesteps; lane = output dim (coalesced WT reads, uniform states reads).
__global__ __launch_bounds__(256) void esn_out_gemm(const float* __restrict__ states,
                                                    const float* __restrict__ WT,
                                                    const float* __restrict__ bout,
                                                    float* __restrict__ out) {
  const int tid  = threadIdx.x;
  const int lane = tid & 63;
  const int grp  = tid >> 6;
  const int t0   = blockIdx.x * 16 + grp * 4;

  float acc0 = 0.f, acc1 = 0.f, acc2 = 0.f, acc3 = 0.f;
  const float* s0 = states + (size_t)(t0 + 0) * NRES;
  const float* s1 = states + (size_t)(t0 + 1) * NRES;
  const float* s2 = states + (size_t)(t0 + 2) * NRES;
  const float* s3 = states + (size_t)(t0 + 3) * NRES;

  for (int k = 0; k < NRES; k += 4) {
    const float4 a = *(const float4*)(s0 + k);
    const float4 b = *(const float4*)(s1 + k);
    const float4 c = *(const float4*)(s2 + k);
    const float4 d = *(const float4*)(s3 + k);
    const float wA = WT[(k + 0) * DOUT + lane];
    const float wB = WT[(k + 1) * DOUT + lane];
    const float wC = WT[(k + 2) * DOUT + lane];
    const float wD = WT[(k + 3) * DOUT + lane];
    acc0 = fmaf(a.x, wA, acc0); acc0 = fmaf(a.y, wB, acc0);
    acc0 = fmaf(a.z, wC, acc0); acc0 = fmaf(a.w, wD, acc0);
    acc1 = fmaf(b.x, wA, acc1); acc1 = fmaf(b.y, wB, acc1);
    acc1 = fmaf(b.z, wC, acc1); acc1 = fmaf(b.w, wD, acc1);
    acc2 = fmaf(c.x, wA, acc2); acc2 = fmaf(c.y, wB, acc2);
    acc2 = fmaf(c.z, wC, acc2); acc2 = fmaf(c.w, wD, acc2);
    acc3 = fmaf(d.x, wA, acc3); acc3 = fmaf(d.y, wB, acc3);
    acc3 = fmaf(d.z, wC, acc3); acc3 = fmaf(d.w, wD, acc3);
  }
  const float bb = bout[lane];
  out[(size_t)(t0 + 0) * DOUT + lane] = acc0 + bb;
  out[(size_t)(t0 + 1) * DOUT + lane] = acc1 + bb;
  out[(size_t)(t0 + 2) * DOUT + lane] = acc2 + bb;
  out[(size_t)(t0 + 3) * DOUT + lane] = acc3 + bb;
}

extern "C" void kernel_launch(void* const* d_in, const int* in_sizes, int n_in,
                              void* d_out, int out_size, void* d_ws, size_t ws_size,
                              hipStream_t stream) {
  const float* u    = (const float*)d_in[0];
  const float* Win  = (const float*)d_in[1];
  const float* W    = (const float*)d_in[2];
  const float* Wout = (const float*)d_in[3];
  const float* bout = (const float*)d_in[4];
  float* out = (float*)d_out;

  char* ws = (char*)d_ws;
  float* states = (float*)ws;
  u64*   ring   = (u64*)(ws + (size_t)T_STEPS * NRES * sizeof(float));
  float* WT     = (float*)(ws + (size_t)T_STEPS * NRES * sizeof(float)
                              + (size_t)3 * NRES * sizeof(u64));

  hipLaunchKernelGGL(esn_init_ring, dim3(12), dim3(512), 0, stream, ring);
  hipLaunchKernelGGL(esn_transpose, dim3((DOUT * NRES) / 256), dim3(256), 0, stream,
                     Wout, WT);
  hipLaunchKernelGGL(esn_scan, dim3(256), dim3(512), 0, stream,
                     u, Win, W, states, ring);
  hipLaunchKernelGGL(esn_out_gemm, dim3(T_STEPS / 16), dim3(256), 0, stream,
                     states, WT, bout, out);
}

// Round 5
// 28353.595 us; speedup vs baseline: 1.3610x; 1.3610x over previous
//
#include <hip/hip_runtime.h>

#define T_STEPS 8192
#define NRES    2048
#define DIN     64
#define DOUT    64

typedef unsigned long long u64;
typedef unsigned int u32;

// ---------------------------------------------------------------------------
// ws layout:
//   [0, 64MB)          : states fp32 [T][NRES]
//   [64MB, +24KB)      : ring    u32 [3][NRES]  (fp32 with low 2 mantissa bits
//                        stomped by step tag t&3; NaN-free by construction)
//   [64MB+24KB, +512KB): WT      fp32 [NRES][DOUT] (W_out transposed)
// ---------------------------------------------------------------------------

// Init tag = 3: slot s (s=0,1,2) is first read expecting tag s, so 3 never
// false-positives; value bits are irrelevant until first publish.
__global__ __launch_bounds__(512) void esn_init_ring(u32* __restrict__ ring) {
  int idx = blockIdx.x * 512 + threadIdx.x;
  if (idx < 3 * NRES) ring[idx] = 3u;
}

__global__ __launch_bounds__(256) void esn_transpose(const float* __restrict__ Wout,
                                                     float* __restrict__ WT) {
  int idx = blockIdx.x * 256 + threadIdx.x;  // 0 .. DOUT*NRES-1
  int d = idx >> 11;                         // / NRES
  int k = idx & (NRES - 1);
  WT[k * DOUT + d] = Wout[idx];
}

// Persistent scan — R1 structure (proven 23.4ms): 256 blocks x 256 threads
// (4 waves). Wave wv owns rows r0=8b+2wv, r0+1. Lane l holds
// W[r][g*256+4l+j] (64 regs).
// Protocol: 3-slot ring of u32; word = fp32(x) with low 2 mantissa bits
// replaced by tag t&3 (error ~2^-22). Relaxed agent-scope atomics (performed
// at LLC -> cross-XCD safe). Reader at step t polls slot (t-1)%3 for tag
// (t-1)&3. Slot occupants t, t+3 differ mod 4, and skew <= 1 step, so no
// stale/future word can match the wanted tag.
__global__ __launch_bounds__(256) void esn_scan(const float* __restrict__ u,
                                                const float* __restrict__ Win,
                                                const float* __restrict__ W,
                                                float* __restrict__ states,
                                                u32* __restrict__ ring) {
  const int tid  = threadIdx.x;
  const int lane = tid & 63;
  const int wv   = tid >> 6;
  const int blk  = blockIdx.x;
  const int r0   = blk * 8 + wv * 2;
  const int r1   = r0 + 1;

  __shared__ float xs[NRES];

  // One-time: this wave's two W rows into registers (coalesced float4).
  float w0[32], w1[32];
#pragma unroll
  for (int g = 0; g < 8; ++g) {
    const float4 a = *(const float4*)(W + (size_t)r0 * NRES + g * 256 + lane * 4);
    w0[g * 4 + 0] = a.x; w0[g * 4 + 1] = a.y; w0[g * 4 + 2] = a.z; w0[g * 4 + 3] = a.w;
    const float4 c = *(const float4*)(W + (size_t)r1 * NRES + g * 256 + lane * 4);
    w1[g * 4 + 0] = c.x; w1[g * 4 + 1] = c.y; w1[g * 4 + 2] = c.z; w1[g * 4 + 3] = c.w;
  }
  const float win0 = Win[r0 * DIN + lane];
  const float win1 = Win[r1 * DIN + lane];

  for (int t = 0; t < T_STEPS; ++t) {
    __syncthreads();  // protect xs against writers while prior step still reads
    if (t == 0) {
#pragma unroll
      for (int j = 0; j < 8; ++j) xs[j * 256 + tid] = 0.0f;
    } else {
      const u32* rb   = ring + ((t + 2) % 3) * NRES;  // slot (t-1)%3
      const u32 want  = (u32)((t - 1) & 3);           // tag of step t-1
      u32 v[8];
#pragma unroll
      for (int j = 0; j < 8; ++j)
        v[j] = __hip_atomic_load(rb + j * 256 + tid, __ATOMIC_RELAXED,
                                 __HIP_MEMORY_SCOPE_AGENT);
      for (;;) {
        bool ok = true;
#pragma unroll
        for (int j = 0; j < 8; ++j) ok = ok && ((v[j] & 3u) == want);
        if (ok) break;
#pragma unroll
        for (int j = 0; j < 8; ++j)
          if ((v[j] & 3u) != want)
            v[j] = __hip_atomic_load(rb + j * 256 + tid, __ATOMIC_RELAXED,
                                     __HIP_MEMORY_SCOPE_AGENT);
      }
#pragma unroll
      for (int j = 0; j < 8; ++j)
        xs[j * 256 + tid] = __uint_as_float(v[j]);
    }
    __syncthreads();

    // acc = W_in[r,:] . u_t  +  W[r,:] . x_{t-1}   (per-lane partial)
    const float uv = u[t * DIN + lane];
    float a0 = win0 * uv;
    float a1 = win1 * uv;
#pragma unroll
    for (int g = 0; g < 8; ++g) {
      const float4 xv = *(const float4*)(xs + g * 256 + lane * 4);
      a0 = fmaf(w0[g * 4 + 0], xv.x, a0);
      a0 = fmaf(w0[g * 4 + 1], xv.y, a0);
      a0 = fmaf(w0[g * 4 + 2], xv.z, a0);
      a0 = fmaf(w0[g * 4 + 3], xv.w, a0);
      a1 = fmaf(w1[g * 4 + 0], xv.x, a1);
      a1 = fmaf(w1[g * 4 + 1], xv.y, a1);
      a1 = fmaf(w1[g * 4 + 2], xv.z, a1);
      a1 = fmaf(w1[g * 4 + 3], xv.w, a1);
    }
    // 64-lane butterfly all-reduce
#pragma unroll
    for (int off = 32; off > 0; off >>= 1) {
      a0 += __shfl_xor(a0, off, 64);
      a1 += __shfl_xor(a1, off, 64);
    }
    if (lane < 2) {
      const float s  = (lane == 0) ? a0 : a1;
      const float xv = tanhf(s);
      const int r    = r0 + lane;
      // stomp low 2 mantissa bits with tag t&3; use same value everywhere
      const u32 word = (__float_as_uint(xv) & ~3u) | (u32)(t & 3);
      states[(size_t)t * NRES + r] = __uint_as_float(word);
      __hip_atomic_store(ring + (t % 3) * NRES + r, word, __ATOMIC_RELAXED,
                         __HIP_MEMORY_SCOPE_AGENT);
    }
  }
}

// Y = states @ W_out^T + b : block = 16 timesteps; each 64-lane group does 4
// timesteps; lane = output dim (coalesced WT reads, uniform states reads).
__global__ __launch_bounds__(256) void esn_out_gemm(const float* __restrict__ states,
                                                    const float* __restrict__ WT,
                                                    const float* __restrict__ bout,
                                                    float* __restrict__ out) {
  const int tid  = threadIdx.x;
  const int lane = tid & 63;
  const int grp  = tid >> 6;
  const int t0   = blockIdx.x * 16 + grp * 4;

  float acc0 = 0.f, acc1 = 0.f, acc2 = 0.f, acc3 = 0.f;
  const float* s0 = states + (size_t)(t0 + 0) * NRES;
  const float* s1 = states + (size_t)(t0 + 1) * NRES;
  const float* s2 = states + (size_t)(t0 + 2) * NRES;
  const float* s3 = states + (size_t)(t0 + 3) * NRES;

  for (int k = 0; k < NRES; k += 4) {
    const float4 a = *(const float4*)(s0 + k);
    const float4 b = *(const float4*)(s1 + k);
    const float4 c = *(const float4*)(s2 + k);
    const float4 d = *(const float4*)(s3 + k);
    const float wA = WT[(k + 0) * DOUT + lane];
    const float wB = WT[(k + 1) * DOUT + lane];
    const float wC = WT[(k + 2) * DOUT + lane];
    const float wD = WT[(k + 3) * DOUT + lane];
    acc0 = fmaf(a.x, wA, acc0); acc0 = fmaf(a.y, wB, acc0);
    acc0 = fmaf(a.z, wC, acc0); acc0 = fmaf(a.w, wD, acc0);
    acc1 = fmaf(b.x, wA, acc1); acc1 = fmaf(b.y, wB, acc1);
    acc1 = fmaf(b.z, wC, acc1); acc1 = fmaf(b.w, wD, acc1);
    acc2 = fmaf(c.x, wA, acc2); acc2 = fmaf(c.y, wB, acc2);
    acc2 = fmaf(c.z, wC, acc2); acc2 = fmaf(c.w, wD, acc2);
    acc3 = fmaf(d.x, wA, acc3); acc3 = fmaf(d.y, wB, acc3);
    acc3 = fmaf(d.z, wC, acc3); acc3 = fmaf(d.w, wD, acc3);
  }
  const float bb = bout[lane];
  out[(size_t)(t0 + 0) * DOUT + lane] = acc0 + bb;
  out[(size_t)(t0 + 1) * DOUT + lane] = acc1 + bb;
  out[(size_t)(t0 + 2) * DOUT + lane] = acc2 + bb;
  out[(size_t)(t0 + 3) * DOUT + lane] = acc3 + bb;
}

extern "C" void kernel_launch(void* const* d_in, const int* in_sizes, int n_in,
                              void* d_out, int out_size, void* d_ws, size_t ws_size,
                              hipStream_t stream) {
  const float* u    = (const float*)d_in[0];
  const float* Win  = (const float*)d_in[1];
  const float* W    = (const float*)d_in[2];
  const float* Wout = (const float*)d_in[3];
  const float* bout = (const float*)d_in[4];
  float* out = (float*)d_out;

  char* ws = (char*)d_ws;
  float* states = (float*)ws;
  u32*   ring   = (u32*)(ws + (size_t)T_STEPS * NRES * sizeof(float));
  float* WT     = (float*)(ws + (size_t)T_STEPS * NRES * sizeof(float)
                              + (size_t)3 * NRES * sizeof(u32));

  hipLaunchKernelGGL(esn_init_ring, dim3(12), dim3(512), 0, stream, ring);
  hipLaunchKernelGGL(esn_transpose, dim3((DOUT * NRES) / 256), dim3(256), 0, stream,
                     Wout, WT);
  hipLaunchKernelGGL(esn_scan, dim3(256), dim3(256), 0, stream,
                     u, Win, W, states, ring);
  hipLaunchKernelGGL(esn_out_gemm, dim3(T_STEPS / 16), dim3(256), 0, stream,
                     states, WT, bout, out);
}

// Round 7
// 25027.858 us; speedup vs baseline: 1.5419x; 1.1329x over previous
//
#include <hip/hip_runtime.h>

#define T_STEPS 8192
#define NRES    2048
#define DIN     64
#define DOUT    64

typedef unsigned long long u64;
typedef unsigned int u32;

// ---------------------------------------------------------------------------
// ws layout:
//   [0, 64MB)          : states fp32 [T][NRES]
//   [64MB, +48KB)      : ring    u64 [3][NRES]  tagged words {val<<32 | tag}
//   [64MB+48KB, +512KB): WT      fp32 [NRES][DOUT] (W_out transposed)
// ---------------------------------------------------------------------------

__global__ __launch_bounds__(512) void esn_init_ring(u64* __restrict__ ring) {
  int idx = blockIdx.x * 512 + threadIdx.x;
  if (idx < 3 * NRES) ring[idx] = 0ull;
}

__global__ __launch_bounds__(256) void esn_transpose(const float* __restrict__ Wout,
                                                     float* __restrict__ WT) {
  int idx = blockIdx.x * 256 + threadIdx.x;  // 0 .. DOUT*NRES-1
  int d = idx >> 11;                         // / NRES
  int k = idx & (NRES - 1);
  WT[k * DOUT + d] = Wout[idx];
}

// Persistent scan — R1 protocol, 4x fewer spinning agents:
// 64 blocks x 512 threads (8 waves). Block b owns rows [32b, 32b+32);
// wave wv owns rows rb = 32b+4wv .. rb+3. Lane l holds W[r][g*256+4l+j]
// for g=0..7, j=0..3, for each of its 4 rows (128 VGPRs of W).
// Protocol (R1, best measured): 3-slot ring of tagged u64 {x_bits<<32|(t+1)},
// relaxed agent-scope atomics (LLC-performed, cross-XCD safe, no fences).
// Reader at step t polls slot (t-1)%3 for tag==t. Cross-block skew <= 1 step
// (full-barrier semantics: entering t+1 requires ALL rows of t published),
// so 3 slots are never overwritten while readable.
__global__ __launch_bounds__(512, 2) void esn_scan(const float* __restrict__ u,
                                                   const float* __restrict__ Win,
                                                   const float* __restrict__ W,
                                                   float* __restrict__ states,
                                                   u64* __restrict__ ring) {
  const int tid  = threadIdx.x;
  const int lane = tid & 63;
  const int wv   = tid >> 6;              // 0..7
  const int rb   = blockIdx.x * 32 + wv * 4;  // first of this wave's 4 rows

  __shared__ float xs[NRES];

  // One-time: this wave's 4 W rows into registers (coalesced float4).
  float w0[32], w1[32], w2[32], w3[32];
#pragma unroll
  for (int g = 0; g < 8; ++g) {
    const float4 a = *(const float4*)(W + (size_t)(rb + 0) * NRES + g * 256 + lane * 4);
    w0[g*4+0] = a.x; w0[g*4+1] = a.y; w0[g*4+2] = a.z; w0[g*4+3] = a.w;
    const float4 b = *(const float4*)(W + (size_t)(rb + 1) * NRES + g * 256 + lane * 4);
    w1[g*4+0] = b.x; w1[g*4+1] = b.y; w1[g*4+2] = b.z; w1[g*4+3] = b.w;
    const float4 c = *(const float4*)(W + (size_t)(rb + 2) * NRES + g * 256 + lane * 4);
    w2[g*4+0] = c.x; w2[g*4+1] = c.y; w2[g*4+2] = c.z; w2[g*4+3] = c.w;
    const float4 d = *(const float4*)(W + (size_t)(rb + 3) * NRES + g * 256 + lane * 4);
    w3[g*4+0] = d.x; w3[g*4+1] = d.y; w3[g*4+2] = d.z; w3[g*4+3] = d.w;
  }
  const float win0 = Win[(rb + 0) * DIN + lane];
  const float win1 = Win[(rb + 1) * DIN + lane];
  const float win2 = Win[(rb + 2) * DIN + lane];
  const float win3 = Win[(rb + 3) * DIN + lane];

  for (int t = 0; t < T_STEPS; ++t) {
    __syncthreads();  // protect xs: all waves done computing previous step
    const float uv = u[t * DIN + lane];  // issue before poll; overlaps the wait
    if (t == 0) {
#pragma unroll
      for (int j = 0; j < 4; ++j) xs[j * 512 + tid] = 0.0f;
    } else {
      const u64* rp  = ring + ((t + 2) % 3) * NRES;  // slot (t-1)%3
      const u32 want = (u32)t;                       // tag written at step t-1
      u64 v[4];
#pragma unroll
      for (int j = 0; j < 4; ++j)
        v[j] = __hip_atomic_load(rp + j * 512 + tid, __ATOMIC_RELAXED,
                                 __HIP_MEMORY_SCOPE_AGENT);
      u32 pend = 0xFu;
      while (pend) {
#pragma unroll
        for (int j = 0; j < 4; ++j) {
          if (pend & (1u << j)) {
            if ((u32)v[j] == want) {   // ready: trickle-stage to LDS now
              xs[j * 512 + tid] = __uint_as_float((u32)(v[j] >> 32));
              pend &= ~(1u << j);
            } else {
              v[j] = __hip_atomic_load(rp + j * 512 + tid, __ATOMIC_RELAXED,
                                       __HIP_MEMORY_SCOPE_AGENT);
            }
          }
        }
      }
    }
    __syncthreads();

    // acc_q = W_in[rq,:] . u_t  +  W[rq,:] . x_{t-1}; one float4 LDS read
    // feeds 16 FMAs (4 rows x 4 elements).
    float a0 = win0 * uv, a1 = win1 * uv, a2 = win2 * uv, a3 = win3 * uv;
#pragma unroll
    for (int g = 0; g < 8; ++g) {
      const float4 xv = *(const float4*)(xs + g * 256 + lane * 4);
      a0 = fmaf(w0[g*4+0], xv.x, a0); a0 = fmaf(w0[g*4+1], xv.y, a0);
      a0 = fmaf(w0[g*4+2], xv.z, a0); a0 = fmaf(w0[g*4+3], xv.w, a0);
      a1 = fmaf(w1[g*4+0], xv.x, a1); a1 = fmaf(w1[g*4+1], xv.y, a1);
      a1 = fmaf(w1[g*4+2], xv.z, a1); a1 = fmaf(w1[g*4+3], xv.w, a1);
      a2 = fmaf(w2[g*4+0], xv.x, a2); a2 = fmaf(w2[g*4+1], xv.y, a2);
      a2 = fmaf(w2[g*4+2], xv.z, a2); a2 = fmaf(w2[g*4+3], xv.w, a2);
      a3 = fmaf(w3[g*4+0], xv.x, a3); a3 = fmaf(w3[g*4+1], xv.y, a3);
      a3 = fmaf(w3[g*4+2], xv.z, a3); a3 = fmaf(w3[g*4+3], xv.w, a3);
    }
    // 4 independent 64-lane butterfly all-reduces (interleaved, latency-hidden)
#pragma unroll
    for (int off = 32; off > 0; off >>= 1) {
      a0 += __shfl_xor(a0, off, 64);
      a1 += __shfl_xor(a1, off, 64);
      a2 += __shfl_xor(a2, off, 64);
      a3 += __shfl_xor(a3, off, 64);
    }
    // tanh computed on all lanes (uniform, no divergent serial chain)
    const float x0 = tanhf(a0), x1 = tanhf(a1), x2 = tanhf(a2), x3 = tanhf(a3);
    if (lane < 4) {
      const float s = (lane == 0) ? x0 : (lane == 1) ? x1 : (lane == 2) ? x2 : x3;
      const int r   = rb + lane;
      states[(size_t)t * NRES + r] = s;       // 16B contiguous per wave
      const u64 word = ((u64)__float_as_uint(s) << 32) | (u32)(t + 1);
      __hip_atomic_store(ring + (t % 3) * NRES + r, word, __ATOMIC_RELAXED,
                         __HIP_MEMORY_SCOPE_AGENT);
    }
  }
}

// Y = states @ W_out^T + b : block = 16 timesteps; each 64-lane group does 4
// timesteps; lane = output dim (coalesced WT reads, uniform states reads).
__global__ __launch_bounds__(256) void esn_out_gemm(const float* __restrict__ states,
                                                    const float* __restrict__ WT,
                                                    const float* __restrict__ bout,
                                                    float* __restrict__ out) {
  const int tid  = threadIdx.x;
  const int lane = tid & 63;
  const int grp  = tid >> 6;
  const int t0   = blockIdx.x * 16 + grp * 4;

  float acc0 = 0.f, acc1 = 0.f, acc2 = 0.f, acc3 = 0.f;
  const float* s0 = states + (size_t)(t0 + 0) * NRES;
  const float* s1 = states + (size_t)(t0 + 1) * NRES;
  const float* s2 = states + (size_t)(t0 + 2) * NRES;
  const float* s3 = states + (size_t)(t0 + 3) * NRES;

  for (int k = 0; k < NRES; k += 4) {
    const float4 a = *(const float4*)(s0 + k);
    const float4 b = *(const float4*)(s1 + k);
    const float4 c = *(const float4*)(s2 + k);
    const float4 d = *(const float4*)(s3 + k);
    const float wA = WT[(k + 0) * DOUT + lane];
    const float wB = WT[(k + 1) * DOUT + lane];
    const float wC = WT[(k + 2) * DOUT + lane];
    const float wD = WT[(k + 3) * DOUT + lane];
    acc0 = fmaf(a.x, wA, acc0); acc0 = fmaf(a.y, wB, acc0);
    acc0 = fmaf(a.z, wC, acc0); acc0 = fmaf(a.w, wD, acc0);
    acc1 = fmaf(b.x, wA, acc1); acc1 = fmaf(b.y, wB, acc1);
    acc1 = fmaf(b.z, wC, acc1); acc1 = fmaf(b.w, wD, acc1);
    acc2 = fmaf(c.x, wA, acc2); acc2 = fmaf(c.y, wB, acc2);
    acc2 = fmaf(c.z, wC, acc2); acc2 = fmaf(c.w, wD, acc2);
    acc3 = fmaf(d.x, wA, acc3); acc3 = fmaf(d.y, wB, acc3);
    acc3 = fmaf(d.z, wC, acc3); acc3 = fmaf(d.w, wD, acc3);
  }
  const float bb = bout[lane];
  out[(size_t)(t0 + 0) * DOUT + lane] = acc0 + bb;
  out[(size_t)(t0 + 1) * DOUT + lane] = acc1 + bb;
  out[(size_t)(t0 + 2) * DOUT + lane] = acc2 + bb;
  out[(size_t)(t0 + 3) * DOUT + lane] = acc3 + bb;
}

extern "C" void kernel_launch(void* const* d_in, const int* in_sizes, int n_in,
                              void* d_out, int out_size, void* d_ws, size_t ws_size,
                              hipStream_t stream) {
  const float* u    = (const float*)d_in[0];
  const float* Win  = (const float*)d_in[1];
  const float* W    = (const float*)d_in[2];
  const float* Wout = (const float*)d_in[3];
  const float* bout = (const float*)d_in[4];
  float* out = (float*)d_out;

  char* ws = (char*)d_ws;
  float* states = (float*)ws;
  u64*   ring   = (u64*)(ws + (size_t)T_STEPS * NRES * sizeof(float));
  float* WT     = (float*)(ws + (size_t)T_STEPS * NRES * sizeof(float)
                              + (size_t)3 * NRES * sizeof(u64));

  hipLaunchKernelGGL(esn_init_ring, dim3(12), dim3(512), 0, stream, ring);
  hipLaunchKernelGGL(esn_transpose, dim3((DOUT * NRES) / 256), dim3(256), 0, stream,
                     Wout, WT);
  hipLaunchKernelGGL(esn_scan, dim3(64), dim3(512), 0, stream,
                     u, Win, W, states, ring);
  hipLaunchKernelGGL(esn_out_gemm, dim3(T_STEPS / 16), dim3(256), 0, stream,
                     states, WT, bout, out);
}